// Round 1
// baseline (682.207 us; speedup 1.0000x reference)
//
#include <hip/hip_runtime.h>
#include <stdint.h>

// Problem constants (fixed by reference): B=128, S=400, H=E=512, 4H=2048, 2H=1024
using short8 = __attribute__((ext_vector_type(8))) short;
using f32x4  = __attribute__((ext_vector_type(4))) float;

__device__ __forceinline__ unsigned short f2b(float x) {
  union { float f; unsigned u; } v; v.f = x;
  unsigned r = v.u + 0x7FFFu + ((v.u >> 16) & 1u);
  return (unsigned short)(r >> 16);
}

// ---------------- small fp32 GEMMs (16x16 output tile, thread-per-output) ----------------

// dec_emb[b,e] = [emb|pctx][b,:] . fcW[e,:] + fcB[e]   (K=1024)
__global__ __launch_bounds__(256) void k_fcdec(const float* __restrict__ emb,
    const float* __restrict__ pctx, const float* __restrict__ W,
    const float* __restrict__ bias, float* __restrict__ outp)
{
  int ni = threadIdx.x & 15, bi = threadIdx.x >> 4;
  int e = (int)(blockIdx.x & 31) * 16 + ni;   // 512/16 = 32
  int b = (int)(blockIdx.x >> 5) * 16 + bi;   // 128/16 = 8  -> grid 256
  const float* wr = W + (size_t)e * 1024;
  const float* xa = emb + (size_t)b * 512;
  const float* xb = pctx + (size_t)b * 512;
  float acc = 0.f;
  #pragma unroll 4
  for (int k = 0; k < 512; k += 4) {
    float4 w = *(const float4*)(wr + k); float4 x = *(const float4*)(xa + k);
    acc += w.x*x.x + w.y*x.y + w.z*x.z + w.w*x.w;
  }
  #pragma unroll 4
  for (int k = 0; k < 512; k += 4) {
    float4 w = *(const float4*)(wr + 512 + k); float4 x = *(const float4*)(xb + k);
    acc += w.x*x.x + w.y*x.y + w.z*x.z + w.w*x.w;
  }
  outp[(size_t)b*512 + e] = acc + bias[e];
}

// gates[b,j] = dec_emb[b,:].Wih[j,:] + h0[b,:].Whh[j,:] + bih[j] + bhh[j]
__global__ __launch_bounds__(256) void k_gates(const float* __restrict__ demb,
    const float* __restrict__ h0, const float* __restrict__ Wih,
    const float* __restrict__ Whh, const float* __restrict__ bih,
    const float* __restrict__ bhh, float* __restrict__ g)
{
  int ni = threadIdx.x & 15, bi = threadIdx.x >> 4;
  int j = (int)(blockIdx.x & 127) * 16 + ni;  // 2048/16 = 128
  int b = (int)(blockIdx.x >> 7) * 16 + bi;   // grid 1024
  const float* w1 = Wih + (size_t)j * 512;
  const float* x1 = demb + (size_t)b * 512;
  const float* w2 = Whh + (size_t)j * 512;
  const float* x2 = h0 + (size_t)b * 512;
  float acc = 0.f;
  #pragma unroll 4
  for (int k = 0; k < 512; k += 4) {
    float4 w = *(const float4*)(w1 + k); float4 x = *(const float4*)(x1 + k);
    acc += w.x*x.x + w.y*x.y + w.z*x.z + w.w*x.w;
  }
  #pragma unroll 4
  for (int k = 0; k < 512; k += 4) {
    float4 w = *(const float4*)(w2 + k); float4 x = *(const float4*)(x2 + k);
    acc += w.x*x.x + w.y*x.y + w.z*x.z + w.w*x.w;
  }
  g[(size_t)b*2048 + j] = acc + bih[j] + bhh[j];
}

// LSTM pointwise
__global__ __launch_bounds__(256) void k_lstm(const float* __restrict__ g,
    const float* __restrict__ c0, float* __restrict__ hout, float* __restrict__ cout)
{
  int t = blockIdx.x * 256 + threadIdx.x;  // 65536
  int b = t >> 9, h = t & 511;
  const float* gr = g + (size_t)b * 2048;
  float gi = gr[h], gf = gr[512 + h], gg = gr[1024 + h], go = gr[1536 + h];
  float si = 1.f / (1.f + expf(-gi));
  float sf = 1.f / (1.f + expf(-gf));
  float so = 1.f / (1.f + expf(-go));
  float c = sf * c0[t] + si * tanhf(gg);
  float hh = so * tanhf(c);
  hout[t] = hh; cout[t] = c;
}

// hq[b,n] = sum_j [h|c][b,j] * attnW[j,n]   (attn_W is (1024,512), NOT transposed)
__global__ __launch_bounds__(256) void k_hq(const float* __restrict__ hn,
    const float* __restrict__ cn, const float* __restrict__ W, float* __restrict__ hq)
{
  int ni = threadIdx.x & 15, bi = threadIdx.x >> 4;
  int n = (int)(blockIdx.x & 7) * 64 + ni * 4;   // 512/64 = 8
  int b = (int)(blockIdx.x >> 3) * 16 + bi;      // grid 64
  const float* xh = hn + (size_t)b * 512;
  const float* xc = cn + (size_t)b * 512;
  float4 a = {0.f, 0.f, 0.f, 0.f};
  for (int j = 0; j < 512; ++j) {
    float4 w = *(const float4*)(W + (size_t)j * 512 + n);
    float x = xh[j];
    a.x += x * w.x; a.y += x * w.y; a.z += x * w.z; a.w += x * w.w;
  }
  for (int j = 0; j < 512; ++j) {
    float4 w = *(const float4*)(W + (size_t)(512 + j) * 512 + n);
    float x = xc[j];
    a.x += x * w.x; a.y += x * w.y; a.z += x * w.z; a.w += x * w.w;
  }
  *(float4*)(hq + (size_t)b * 512 + n) = a;
}

// W2T[n,h] = bf16(W2[h,n])  (transpose + convert, LDS 32x32 tiles)
__global__ __launch_bounds__(256) void k_w2t(const float* __restrict__ w2,
    unsigned short* __restrict__ w2t)
{
  __shared__ float tile[32][33];
  int bx = blockIdx.x & 15, by = blockIdx.x >> 4;  // n-tile, h-tile
  int h0 = by * 32, n0 = bx * 32;
  int tx = threadIdx.x & 31, ty = threadIdx.x >> 5;  // 32 x 8
  #pragma unroll
  for (int i = 0; i < 32; i += 8)
    tile[ty + i][tx] = w2[(size_t)(h0 + ty + i) * 512 + n0 + tx];
  __syncthreads();
  #pragma unroll
  for (int i = 0; i < 32; i += 8)
    w2t[(size_t)(n0 + ty + i) * 512 + h0 + tx] = f2b(tile[tx][ty + i]);
}

// ---------------- energy GEMM + fused tanh/W3 epilogue ----------------
// rows r = s*128+b of enc (51200 x 512); P = enc @ W2 (bf16 MFMA, f32 acc)
// att[b,s] = sum_n W3[n]*tanh(P[r,n] + hq[b,n] + cov[b,s]*cw[n])
// block: 32 rows x 512 cols, 4 waves (wave w owns n in [w*128, w*128+128))
__global__ __launch_bounds__(256) void k_energy(const float* __restrict__ enc,
    const unsigned short* __restrict__ w2t, const float* __restrict__ hq,
    const float* __restrict__ cov, const float* __restrict__ cw,
    const float* __restrict__ w3, float* __restrict__ att)
{
  __shared__ unsigned short As[4][32][8];   // [kchunk][row][8] bf16
  __shared__ float part[4][32];
  int tid = threadIdx.x;
  int wave = tid >> 6, lane = tid & 63, l15 = lane & 15, l4 = lane >> 4;
  int r0 = (int)blockIdx.x * 32;

  f32x4 acc[2][8];
  #pragma unroll
  for (int i = 0; i < 2; ++i)
    #pragma unroll
    for (int j = 0; j < 8; ++j) { f32x4 z = {0.f,0.f,0.f,0.f}; acc[i][j] = z; }

  int srow = tid >> 3, sc4 = (tid & 7) * 4;
  for (int k0 = 0; k0 < 512; k0 += 32) {
    __syncthreads();
    {
      float4 v = *(const float4*)(enc + (size_t)(r0 + srow) * 512 + k0 + sc4);
      ushort4 hv; hv.x = f2b(v.x); hv.y = f2b(v.y); hv.z = f2b(v.z); hv.w = f2b(v.w);
      *(ushort4*)&As[sc4 >> 3][srow][sc4 & 7] = hv;
    }
    __syncthreads();
    short8 bf[8];
    const unsigned short* wp = w2t + (size_t)(wave * 128 + l15) * 512 + k0 + l4 * 8;
    #pragma unroll
    for (int j = 0; j < 8; ++j)
      bf[j] = *(const short8*)(wp + (size_t)j * 16 * 512);
    short8 af0 = *(const short8*)&As[l4][l15][0];
    short8 af1 = *(const short8*)&As[l4][16 + l15][0];
    #pragma unroll
    for (int j = 0; j < 8; ++j) {
      acc[0][j] = __builtin_amdgcn_mfma_f32_16x16x32_bf16(af0, bf[j], acc[0][j], 0, 0, 0);
      acc[1][j] = __builtin_amdgcn_mfma_f32_16x16x32_bf16(af1, bf[j], acc[1][j], 0, 0, 0);
    }
  }

  // epilogue: tanh + W3 dot, per-row reduce
  #pragma unroll
  for (int i = 0; i < 2; ++i) {
    #pragma unroll
    for (int q = 0; q < 4; ++q) {
      int rl = i * 16 + l4 * 4 + q;
      int rg = r0 + rl;
      int b = rg & 127, s = rg >> 7;
      float cv = cov[b * 400 + s];
      float sum = 0.f;
      #pragma unroll
      for (int j = 0; j < 8; ++j) {
        int n = wave * 128 + j * 16 + l15;
        float e = acc[i][j][q] + hq[b * 512 + n] + cv * cw[n];
        sum += tanhf(e) * w3[n];
      }
      sum += __shfl_xor(sum, 1, 64);
      sum += __shfl_xor(sum, 2, 64);
      sum += __shfl_xor(sum, 4, 64);
      sum += __shfl_xor(sum, 8, 64);
      if (l15 == 0) part[wave][rl] = sum;
    }
  }
  __syncthreads();
  if (tid < 32) {
    int rg = r0 + tid;
    float a = part[0][tid] + part[1][tid] + part[2][tid] + part[3][tid];
    int b = rg & 127, s = rg >> 7;
    att[b * 400 + s] = a;
  }
}

// attention mask + softmax over S=400, writes enc_attn
__global__ __launch_bounds__(256) void k_asoftmax(const float* __restrict__ att,
    const float* __restrict__ mask, float* __restrict__ outp)
{
  __shared__ float red[256];
  int b = blockIdx.x, t = threadIdx.x;
  int s1 = t + 256;
  float a0 = -1e30f, a1 = -1e30f;
  if (t < 400) { float m = mask[b*400 + t]; a0 = m * att[b*400 + t] - (1.f - m) * 1e20f; }
  if (s1 < 400) { float m = mask[b*400 + s1]; a1 = m * att[b*400 + s1] - (1.f - m) * 1e20f; }
  red[t] = fmaxf(a0, a1); __syncthreads();
  for (int off = 128; off; off >>= 1) { if (t < off) red[t] = fmaxf(red[t], red[t + off]); __syncthreads(); }
  float mx = red[0]; __syncthreads();
  float e0 = (t < 400) ? expf(a0 - mx) : 0.f;
  float e1 = (s1 < 400) ? expf(a1 - mx) : 0.f;
  red[t] = e0 + e1; __syncthreads();
  for (int off = 128; off; off >>= 1) { if (t < off) red[t] += red[t + off]; __syncthreads(); }
  float inv = 1.f / red[0];
  if (t < 400) outp[b*400 + t] = e0 * inv;
  if (s1 < 400) outp[b*400 + s1] = e1 * inv;
}

// enc_context[b,h] = sum_s enc[s,b,h] * enc_attn[b,s]
__global__ __launch_bounds__(256) void k_ctx(const float* __restrict__ enc,
    const float* __restrict__ attn, float* __restrict__ ctx)
{
  __shared__ float aw[400];
  int b = (int)blockIdx.x >> 1;
  int h = ((int)(blockIdx.x & 1) << 8) + threadIdx.x;
  for (int s = threadIdx.x; s < 400; s += 256) aw[s] = attn[b*400 + s];
  __syncthreads();
  float acc = 0.f;
  #pragma unroll 4
  for (int s = 0; s < 400; ++s)
    acc += enc[((size_t)s * 128 + b) * 512 + h] * aw[s];
  ctx[(size_t)b * 512 + h] = acc;
}

// build combined (bf16) + pointer prob
__global__ __launch_bounds__(256) void k_comb(const float* __restrict__ hn,
    const float* __restrict__ ctx, const float* __restrict__ emb,
    const float* __restrict__ ptrW, const float* __restrict__ ptrB,
    unsigned short* __restrict__ comb, float* __restrict__ probptr)
{
  __shared__ float red[256];
  int b = blockIdx.x, t = threadIdx.x;
  for (int n = t; n < 1024; n += 256) {
    float x = (n < 512) ? hn[b*512 + n] : ctx[b*512 + n - 512];
    comb[(size_t)b*1024 + n] = f2b(x);
  }
  float a = 0.f;
  for (int k = t; k < 2048; k += 256) {
    float x = (k < 512) ? hn[b*512 + k]
            : (k < 1024) ? ctx[b*512 + k - 512]
            : (k < 1536) ? emb[b*512 + k - 1024]
            : hn[b*512 + k - 1536];
    a += x * ptrW[k];
  }
  red[t] = a; __syncthreads();
  for (int off = 128; off; off >>= 1) { if (t < off) red[t] += red[t + off]; __syncthreads(); }
  if (t == 0) probptr[b] = 1.f / (1.f + expf(-(red[0] + ptrB[0])));
}

// ---------------- logits GEMM: (128 x 1024) @ out_W^T -> (128 x V), bf16 MFMA ----------------
// block: all 128 b-rows x 64 vocab cols, 4 waves (wave w owns 16 cols)
__global__ __launch_bounds__(256) void k_logits(const unsigned short* __restrict__ comb,
    const float* __restrict__ outW, float* __restrict__ logits, int V)
{
  __shared__ unsigned short As[4][128][8];  // 8KB
  int tid = threadIdx.x;
  int wave = tid >> 6, lane = tid & 63, l15 = lane & 15, l4 = lane >> 4;
  int v0 = (int)blockIdx.x * 64;
  int v = v0 + wave * 16 + l15;
  int vc = (v < V) ? v : (V - 1);

  f32x4 acc[8];
  #pragma unroll
  for (int i = 0; i < 8; ++i) { f32x4 z = {0.f,0.f,0.f,0.f}; acc[i] = z; }

  int row = tid >> 1, c = (tid & 1) * 16;
  for (int k0 = 0; k0 < 1024; k0 += 32) {
    __syncthreads();
    {
      uint4 s0 = *(const uint4*)(comb + (size_t)row * 1024 + k0 + c);
      uint4 s1 = *(const uint4*)(comb + (size_t)row * 1024 + k0 + c + 8);
      *(uint4*)&As[c >> 3][row][0] = s0;
      *(uint4*)&As[(c >> 3) + 1][row][0] = s1;
    }
    __syncthreads();
    const float* wp = outW + (size_t)vc * 1024 + k0 + l4 * 8;
    float4 f0 = *(const float4*)wp;
    float4 f1 = *(const float4*)(wp + 4);
    short8 bf;
    bf[0] = (short)f2b(f0.x); bf[1] = (short)f2b(f0.y);
    bf[2] = (short)f2b(f0.z); bf[3] = (short)f2b(f0.w);
    bf[4] = (short)f2b(f1.x); bf[5] = (short)f2b(f1.y);
    bf[6] = (short)f2b(f1.z); bf[7] = (short)f2b(f1.w);
    #pragma unroll
    for (int i = 0; i < 8; ++i) {
      short8 af = *(const short8*)&As[l4][i * 16 + l15][0];
      acc[i] = __builtin_amdgcn_mfma_f32_16x16x32_bf16(af, bf, acc[i], 0, 0, 0);
    }
  }
  if (v < V) {
    #pragma unroll
    for (int i = 0; i < 8; ++i)
      #pragma unroll
      for (int q = 0; q < 4; ++q)
        logits[(size_t)(i * 16 + l4 * 4 + q) * V + v] = acc[i][q];
  }
}

// per-row online max + sum(exp)
__global__ __launch_bounds__(256) void k_rowstat(const float* __restrict__ logits,
    float* __restrict__ rmax, float* __restrict__ rsum, int V)
{
  __shared__ float rm[256], rs[256];
  int b = blockIdx.x, t = threadIdx.x;
  float m = -1e30f, s = 0.f;
  for (int v = t; v < V; v += 256) {
    float x = logits[(size_t)b * V + v];
    if (x > m) { s = s * expf(m - x) + 1.f; m = x; }
    else s += expf(x - m);
  }
  rm[t] = m; rs[t] = s; __syncthreads();
  for (int off = 128; off; off >>= 1) {
    if (t < off) {
      float m1 = rm[t], s1 = rs[t], m2 = rm[t + off], s2 = rs[t + off];
      float M = fmaxf(m1, m2);
      rm[t] = M; rs[t] = s1 * expf(m1 - M) + s2 * expf(m2 - M);
    }
    __syncthreads();
  }
  if (t == 0) { rmax[b] = rm[0]; rsum[b] = rs[0]; }
}

// out[b, v<V] = (1-p_ptr)*softmax(logits); out[b, V..ext) = 0
__global__ void k_probs(const float* __restrict__ logits, const float* __restrict__ rmax,
    const float* __restrict__ rsum, const float* __restrict__ probptr,
    float* __restrict__ outp, int V, int ext)
{
  int b = blockIdx.y;
  int v = (int)blockIdx.x * 256 + threadIdx.x;
  if (v >= ext) return;
  float val = 0.f;
  if (v < V) {
    float pg = 1.f - probptr[b];
    val = pg * expf(logits[(size_t)b * V + v] - rmax[b]) / rsum[b];
  }
  outp[(size_t)b * ext + v] = val;
}

// scatter-add pointer mass
__global__ void k_scatter(const int* __restrict__ widx, const float* __restrict__ attn,
    const float* __restrict__ probptr, float* __restrict__ outp, int ext)
{
  int i = (int)blockIdx.x * 256 + threadIdx.x;  // 51200
  if (i >= 128 * 400) return;
  int b = i / 400;
  atomicAdd(&outp[(size_t)b * ext + widx[i]], probptr[b] * attn[i]);
}

__global__ void k_log(float* __restrict__ outp, int n)
{
  int i = (int)blockIdx.x * 256 + threadIdx.x;
  if (i < n) outp[i] = logf(outp[i] + 1e-31f);
}

// ---------------- host ----------------
extern "C" void kernel_launch(void* const* d_in, const int* in_sizes, int n_in,
                              void* d_out, int out_size, void* d_ws, size_t ws_size,
                              hipStream_t stream) {
  const float* emb   = (const float*)d_in[0];
  const float* h0    = (const float*)d_in[1];
  const float* c0    = (const float*)d_in[2];
  const float* enc   = (const float*)d_in[3];
  const float* cov   = (const float*)d_in[4];
  const float* mask  = (const float*)d_in[5];
  const int*   widx  = (const int*)d_in[6];
  const float* pctx  = (const float*)d_in[7];
  const float* fcW   = (const float*)d_in[9];
  const float* fcB   = (const float*)d_in[10];
  const float* Wih   = (const float*)d_in[11];
  const float* Whh   = (const float*)d_in[12];
  const float* bih   = (const float*)d_in[13];
  const float* bhh   = (const float*)d_in[14];
  const float* attnW = (const float*)d_in[15];
  const float* W2    = (const float*)d_in[16];
  const float* W3    = (const float*)d_in[17];
  const float* cw    = (const float*)d_in[18];
  const float* ptrW  = (const float*)d_in[19];
  const float* ptrB  = (const float*)d_in[20];
  const float* outW  = (const float*)d_in[21];

  const int V   = in_sizes[21] / 1024;               // 50000
  const int ext = (out_size - 128 * (1024 + 400 + 1)) / 128;  // 50100

  float* F       = (float*)d_ws;
  float* dec_emb = F;                 // 65536
  float* gates   = F + 65536;         // 262144
  float* hq      = F + 327680;        // 65536
  float* ctx     = F + 393216;        // 65536
  float* att     = F + 458752;        // 51200
  float* rmax    = F + 509952;        // 128
  float* rsum    = F + 510080;        // 128
  unsigned short* w2t  = (unsigned short*)(F + 510208);  // 262144 bf16
  unsigned short* comb = (unsigned short*)(F + 641280);  // 131072 bf16
  float* logits  = F + 706816;        // 128*V

  float* outp    = (float*)d_out;
  float* o_probs = outp;
  float* o_h     = outp + (size_t)128 * ext;
  float* o_c     = o_h + 65536;
  float* o_attn  = o_c + 65536;
  float* o_pp    = o_attn + 51200;

  k_fcdec   <<<256, 256, 0, stream>>>(emb, pctx, fcW, fcB, dec_emb);
  k_gates   <<<1024, 256, 0, stream>>>(dec_emb, h0, Wih, Whh, bih, bhh, gates);
  k_lstm    <<<256, 256, 0, stream>>>(gates, c0, o_h, o_c);
  k_hq      <<<64, 256, 0, stream>>>(o_h, o_c, attnW, hq);
  k_w2t     <<<256, 256, 0, stream>>>(W2, w2t);
  k_energy  <<<1600, 256, 0, stream>>>(enc, w2t, hq, cov, cw, W3, att);
  k_asoftmax<<<128, 256, 0, stream>>>(att, mask, o_attn);
  k_ctx     <<<256, 256, 0, stream>>>(enc, o_attn, ctx);
  k_comb    <<<128, 256, 0, stream>>>(o_h, ctx, emb, ptrW, ptrB, comb, o_pp);
  k_logits  <<<(V + 63) / 64, 256, 0, stream>>>(comb, outW, logits, V);
  k_rowstat <<<128, 256, 0, stream>>>(logits, rmax, rsum, V);
  dim3 gp((ext + 255) / 256, 128);
  k_probs   <<<gp, 256, 0, stream>>>(logits, rmax, rsum, o_pp, o_probs, V, ext);
  k_scatter <<<200, 256, 0, stream>>>(widx, o_attn, o_pp, o_probs, ext);
  k_log     <<<(128 * ext + 255) / 256, 256, 0, stream>>>(o_probs, 128 * ext);
}

// Round 3
// 639.617 us; speedup vs baseline: 1.0666x; 1.0666x over previous
//
#include <hip/hip_runtime.h>
#include <stdint.h>

// B=128, S=400, H=E=512, 4H=2048, 2H=1024, V=50000
using short8 = __attribute__((ext_vector_type(8))) short;
using f32x4  = __attribute__((ext_vector_type(4))) float;

__device__ __forceinline__ unsigned short f2b(float x) {
  union { float f; unsigned u; } v; v.f = x;
  unsigned r = v.u + 0x7FFFu + ((v.u >> 16) & 1u);
  return (unsigned short)(r >> 16);
}

__device__ __forceinline__ float fast_tanh(float e) {
  float ex = __expf(e + e);
  return 1.f - 2.f * __builtin_amdgcn_rcpf(ex + 1.f);
}

// ---------------- small fp32 GEMMs (round-1 proven) ----------------

__global__ __launch_bounds__(256) void k_fcdec(const float* __restrict__ emb,
    const float* __restrict__ pctx, const float* __restrict__ W,
    const float* __restrict__ bias, float* __restrict__ outp)
{
  int ni = threadIdx.x & 15, bi = threadIdx.x >> 4;
  int e = (int)(blockIdx.x & 31) * 16 + ni;
  int b = (int)(blockIdx.x >> 5) * 16 + bi;
  const float* wr = W + (size_t)e * 1024;
  const float* xa = emb + (size_t)b * 512;
  const float* xb = pctx + (size_t)b * 512;
  float acc = 0.f;
  #pragma unroll 4
  for (int k = 0; k < 512; k += 4) {
    float4 w = *(const float4*)(wr + k); float4 x = *(const float4*)(xa + k);
    acc += w.x*x.x + w.y*x.y + w.z*x.z + w.w*x.w;
  }
  #pragma unroll 4
  for (int k = 0; k < 512; k += 4) {
    float4 w = *(const float4*)(wr + 512 + k); float4 x = *(const float4*)(xb + k);
    acc += w.x*x.x + w.y*x.y + w.z*x.z + w.w*x.w;
  }
  outp[(size_t)b*512 + e] = acc + bias[e];
}

__global__ __launch_bounds__(256) void k_gates(const float* __restrict__ demb,
    const float* __restrict__ h0, const float* __restrict__ Wih,
    const float* __restrict__ Whh, const float* __restrict__ bih,
    const float* __restrict__ bhh, float* __restrict__ g)
{
  int ni = threadIdx.x & 15, bi = threadIdx.x >> 4;
  int j = (int)(blockIdx.x & 127) * 16 + ni;
  int b = (int)(blockIdx.x >> 7) * 16 + bi;
  const float* w1 = Wih + (size_t)j * 512;
  const float* x1 = demb + (size_t)b * 512;
  const float* w2 = Whh + (size_t)j * 512;
  const float* x2 = h0 + (size_t)b * 512;
  float acc = 0.f;
  #pragma unroll 4
  for (int k = 0; k < 512; k += 4) {
    float4 w = *(const float4*)(w1 + k); float4 x = *(const float4*)(x1 + k);
    acc += w.x*x.x + w.y*x.y + w.z*x.z + w.w*x.w;
  }
  #pragma unroll 4
  for (int k = 0; k < 512; k += 4) {
    float4 w = *(const float4*)(w2 + k); float4 x = *(const float4*)(x2 + k);
    acc += w.x*x.x + w.y*x.y + w.z*x.z + w.w*x.w;
  }
  g[(size_t)b*2048 + j] = acc + bih[j] + bhh[j];
}

__global__ __launch_bounds__(256) void k_lstm(const float* __restrict__ g,
    const float* __restrict__ c0, float* __restrict__ hout, float* __restrict__ cout)
{
  int t = blockIdx.x * 256 + threadIdx.x;
  int b = t >> 9, h = t & 511;
  const float* gr = g + (size_t)b * 2048;
  float gi = gr[h], gf = gr[512 + h], gg = gr[1024 + h], go = gr[1536 + h];
  float si = 1.f / (1.f + expf(-gi));
  float sf = 1.f / (1.f + expf(-gf));
  float so = 1.f / (1.f + expf(-go));
  float c = sf * c0[t] + si * tanhf(gg);
  float hh = so * tanhf(c);
  hout[t] = hh; cout[t] = c;
}

__global__ __launch_bounds__(256) void k_hq(const float* __restrict__ hn,
    const float* __restrict__ cn, const float* __restrict__ W, float* __restrict__ hq)
{
  int ni = threadIdx.x & 15, bi = threadIdx.x >> 4;
  int n = (int)(blockIdx.x & 7) * 64 + ni * 4;
  int b = (int)(blockIdx.x >> 3) * 16 + bi;
  const float* xh = hn + (size_t)b * 512;
  const float* xc = cn + (size_t)b * 512;
  float4 a = {0.f, 0.f, 0.f, 0.f};
  for (int j = 0; j < 512; ++j) {
    float4 w = *(const float4*)(W + (size_t)j * 512 + n);
    float x = xh[j];
    a.x += x * w.x; a.y += x * w.y; a.z += x * w.z; a.w += x * w.w;
  }
  for (int j = 0; j < 512; ++j) {
    float4 w = *(const float4*)(W + (size_t)(512 + j) * 512 + n);
    float x = xc[j];
    a.x += x * w.x; a.y += x * w.y; a.z += x * w.z; a.w += x * w.w;
  }
  *(float4*)(hq + (size_t)b * 512 + n) = a;
}

// W2T[n,h] = bf16(W2[h,n])
__global__ __launch_bounds__(256) void k_w2t(const float* __restrict__ w2,
    unsigned short* __restrict__ w2t)
{
  __shared__ float tile[32][33];
  int bx = blockIdx.x & 15, by = blockIdx.x >> 4;
  int h0 = by * 32, n0 = bx * 32;
  int tx = threadIdx.x & 31, ty = threadIdx.x >> 5;
  #pragma unroll
  for (int i = 0; i < 32; i += 8)
    tile[ty + i][tx] = w2[(size_t)(h0 + ty + i) * 512 + n0 + tx];
  __syncthreads();
  #pragma unroll
  for (int i = 0; i < 32; i += 8)
    w2t[(size_t)(n0 + ty + i) * 512 + h0 + tx] = f2b(tile[tx][ty + i]);
}

// ---------------- energy GEMM (128x128 tile, BK=32, reg-staged, padded LDS) ----------------
// grid 1600: nt = bid&3, rt = bid>>2. rows r0..r0+127 are (s=rt, b=0..127).
// att4[nt*51200 + b*400 + rt] = sum_{n in nt-slice} w3[n]*tanh(P + hq + cov*cw)
#define LDP 40   // padded row stride in bf16 elements (80B)
__global__ __launch_bounds__(256) void k_energy(const float* __restrict__ enc,
    const unsigned short* __restrict__ w2t, const float* __restrict__ hq,
    const float* __restrict__ cov, const float* __restrict__ cw,
    const float* __restrict__ w3, float* __restrict__ att4)
{
  __shared__ unsigned short Al[128 * LDP];   // 10KB
  __shared__ unsigned short Bl[128 * LDP];   // 10KB
  __shared__ float part[2][128];

  int tid = threadIdx.x;
  int lane = tid & 63, wave = tid >> 6;
  int l15 = lane & 15, l4 = lane >> 4;
  int wr = wave >> 1, wc = wave & 1;

  int nt = (int)blockIdx.x & 3, rt = (int)blockIdx.x >> 2;
  int r0 = rt * 128, n0 = nt * 128;

  f32x4 acc[4][4];
  #pragma unroll
  for (int i = 0; i < 4; ++i)
    #pragma unroll
    for (int j = 0; j < 4; ++j) { f32x4 z = {0.f,0.f,0.f,0.f}; acc[i][j] = z; }

  for (int k0 = 0; k0 < 512; k0 += 32) {
    __syncthreads();
    #pragma unroll
    for (int i = 0; i < 2; ++i) {
      int s = tid + i * 256;        // 512 slots of 8 bf16
      int row = s >> 2, c = s & 3;
      const float* asrc = enc + (size_t)(r0 + row) * 512 + k0 + c * 8;
      float4 f0 = *(const float4*)asrc;
      float4 f1 = *(const float4*)(asrc + 4);
      short8 av;
      av[0] = (short)f2b(f0.x); av[1] = (short)f2b(f0.y);
      av[2] = (short)f2b(f0.z); av[3] = (short)f2b(f0.w);
      av[4] = (short)f2b(f1.x); av[5] = (short)f2b(f1.y);
      av[6] = (short)f2b(f1.z); av[7] = (short)f2b(f1.w);
      *(short8*)(Al + row * LDP + c * 8) = av;
      short8 bv = *(const short8*)(w2t + (size_t)(n0 + row) * 512 + k0 + c * 8);
      *(short8*)(Bl + row * LDP + c * 8) = bv;
    }
    __syncthreads();

    short8 a[4], bfr[4];
    #pragma unroll
    for (int ar = 0; ar < 4; ++ar)
      a[ar] = *(const short8*)(Al + (wr * 64 + ar * 16 + l15) * LDP + l4 * 8);
    #pragma unroll
    for (int bc = 0; bc < 4; ++bc)
      bfr[bc] = *(const short8*)(Bl + (wc * 64 + bc * 16 + l15) * LDP + l4 * 8);
    #pragma unroll
    for (int ar = 0; ar < 4; ++ar)
      #pragma unroll
      for (int bc = 0; bc < 4; ++bc)
        acc[ar][bc] = __builtin_amdgcn_mfma_f32_16x16x32_bf16(a[ar], bfr[bc], acc[ar][bc], 0, 0, 0);
  }

  // fused epilogue: tanh + W3 dot, reduce over n
  float w3v[4], cwv[4]; int ng[4];
  #pragma unroll
  for (int bc = 0; bc < 4; ++bc) {
    ng[bc] = n0 + wc * 64 + bc * 16 + l15;
    w3v[bc] = w3[ng[bc]]; cwv[bc] = cw[ng[bc]];
  }
  #pragma unroll
  for (int ar = 0; ar < 4; ++ar) {
    #pragma unroll
    for (int q = 0; q < 4; ++q) {
      int bb = wr * 64 + ar * 16 + l4 * 4 + q;   // local row == batch index
      float cv = cov[bb * 400 + rt];
      const float* hqb = hq + (size_t)bb * 512;
      float sum = 0.f;
      #pragma unroll
      for (int bc = 0; bc < 4; ++bc) {
        float e = acc[ar][bc][q] + hqb[ng[bc]] + cv * cwv[bc];
        sum += fast_tanh(e) * w3v[bc];
      }
      sum += __shfl_xor(sum, 1, 64);
      sum += __shfl_xor(sum, 2, 64);
      sum += __shfl_xor(sum, 4, 64);
      sum += __shfl_xor(sum, 8, 64);
      if (l15 == 0) part[wc][bb] = sum;
    }
  }
  __syncthreads();
  if (tid < 128)
    att4[(size_t)nt * 51200 + tid * 400 + rt] = part[0][tid] + part[1][tid];
}

// mask + softmax over S=400 (sums the 4 n-tile partials)
__global__ __launch_bounds__(256) void k_asoftmax(const float* __restrict__ att4,
    const float* __restrict__ mask, float* __restrict__ outp)
{
  __shared__ float red[256];
  int b = blockIdx.x, t = threadIdx.x;
  int s1 = t + 256;
  float a0 = -1e30f, a1 = -1e30f;
  if (t < 400) {
    float raw = att4[b*400 + t] + att4[51200 + b*400 + t]
              + att4[102400 + b*400 + t] + att4[153600 + b*400 + t];
    float m = mask[b*400 + t];
    a0 = m * raw - (1.f - m) * 1e20f;
  }
  if (s1 < 400) {
    float raw = att4[b*400 + s1] + att4[51200 + b*400 + s1]
              + att4[102400 + b*400 + s1] + att4[153600 + b*400 + s1];
    float m = mask[b*400 + s1];
    a1 = m * raw - (1.f - m) * 1e20f;
  }
  red[t] = fmaxf(a0, a1); __syncthreads();
  for (int off = 128; off; off >>= 1) { if (t < off) red[t] = fmaxf(red[t], red[t + off]); __syncthreads(); }
  float mx = red[0]; __syncthreads();
  float e0 = (t < 400) ? expf(a0 - mx) : 0.f;
  float e1 = (s1 < 400) ? expf(a1 - mx) : 0.f;
  red[t] = e0 + e1; __syncthreads();
  for (int off = 128; off; off >>= 1) { if (t < off) red[t] += red[t + off]; __syncthreads(); }
  float inv = 1.f / red[0];
  if (t < 400) outp[b*400 + t] = e0 * inv;
  if (s1 < 400) outp[b*400 + s1] = e1 * inv;
}

// enc_context partials: ctx4[sp][b][h], sp covers 100 s each
__global__ __launch_bounds__(256) void k_ctx(const float* __restrict__ enc,
    const float* __restrict__ attn, float* __restrict__ ctx4)
{
  __shared__ float aw[100];
  int b = (int)blockIdx.x >> 2, sp = (int)blockIdx.x & 3;
  if (threadIdx.x < 100) aw[threadIdx.x] = attn[b*400 + sp*100 + threadIdx.x];
  __syncthreads();
  int h = threadIdx.x * 2;
  float ax = 0.f, ay = 0.f;
  for (int i = 0; i < 100; ++i) {
    int s = sp * 100 + i;
    float2 v = *(const float2*)(enc + ((size_t)s * 128 + b) * 512 + h);
    ax += v.x * aw[i]; ay += v.y * aw[i];
  }
  float2 o = {ax, ay};
  *(float2*)(ctx4 + ((size_t)sp * 128 + b) * 512 + h) = o;
}

// build combined (bf16, summing ctx4 partials) + pointer prob
__global__ __launch_bounds__(256) void k_comb(const float* __restrict__ hn,
    const float* __restrict__ ctx4, const float* __restrict__ emb,
    const float* __restrict__ ptrW, const float* __restrict__ ptrB,
    unsigned short* __restrict__ comb, float* __restrict__ probptr)
{
  __shared__ float red[256];
  int b = blockIdx.x, t = threadIdx.x;
  for (int n = t; n < 512; n += 256)
    comb[(size_t)b*1024 + n] = f2b(hn[b*512 + n]);
  float acc = 0.f;
  for (int k = t; k < 2048; k += 256) {
    float x;
    if (k < 512) x = hn[b*512 + k];
    else if (k < 1024) {
      int n = k - 512;
      size_t o = (size_t)b*512 + n;
      x = ctx4[o] + ctx4[65536 + o] + ctx4[131072 + o] + ctx4[196608 + o];
      comb[(size_t)b*1024 + 512 + n] = f2b(x);
    }
    else if (k < 1536) x = emb[b*512 + (k - 1024)];
    else x = hn[b*512 + (k - 1536)];
    acc += x * ptrW[k];
  }
  red[t] = acc; __syncthreads();
  for (int off = 128; off; off >>= 1) { if (t < off) red[t] += red[t + off]; __syncthreads(); }
  if (t == 0) probptr[b] = 1.f / (1.f + expf(-(red[0] + ptrB[0])));
}

// ---------------- logits GEMM: barrier-free, frags direct from global ----------------
__global__ __launch_bounds__(256) void k_logits(const unsigned short* __restrict__ comb,
    const float* __restrict__ outW, float* __restrict__ logits, int V)
{
  int tid = threadIdx.x, lane = tid & 63, wave = tid >> 6;
  int l15 = lane & 15, l4 = lane >> 4;
  int v = (int)blockIdx.x * 64 + wave * 16 + l15;
  int vc = (v < V) ? v : (V - 1);

  f32x4 acc[8];
  #pragma unroll
  for (int i = 0; i < 8; ++i) { f32x4 z = {0.f,0.f,0.f,0.f}; acc[i] = z; }

  const float* wp = outW + (size_t)vc * 1024 + l4 * 8;
  const unsigned short* cb = comb + (size_t)l15 * 1024 + l4 * 8;

  #pragma unroll 2
  for (int k0 = 0; k0 < 1024; k0 += 32) {
    float4 f0 = *(const float4*)(wp + k0);
    float4 f1 = *(const float4*)(wp + k0 + 4);
    short8 bf;
    bf[0] = (short)f2b(f0.x); bf[1] = (short)f2b(f0.y);
    bf[2] = (short)f2b(f0.z); bf[3] = (short)f2b(f0.w);
    bf[4] = (short)f2b(f1.x); bf[5] = (short)f2b(f1.y);
    bf[6] = (short)f2b(f1.z); bf[7] = (short)f2b(f1.w);
    #pragma unroll
    for (int i = 0; i < 8; ++i) {
      short8 af = *(const short8*)(cb + (size_t)i * 16 * 1024 + k0);
      acc[i] = __builtin_amdgcn_mfma_f32_16x16x32_bf16(af, bf, acc[i], 0, 0, 0);
    }
  }
  if (v < V) {
    #pragma unroll
    for (int i = 0; i < 8; ++i) {
      int rbase = i * 16 + l4 * 4;
      #pragma unroll
      for (int q = 0; q < 4; ++q)
        logits[(size_t)(rbase + q) * V + v] = acc[i][q];
    }
  }
}

__global__ __launch_bounds__(256) void k_rowstat(const float* __restrict__ logits,
    float* __restrict__ rmax, float* __restrict__ rsum, int V)
{
  __shared__ float rm[256], rs[256];
  int b = blockIdx.x, t = threadIdx.x;
  float m = -1e30f, s = 0.f;
  for (int v = t; v < V; v += 256) {
    float x = logits[(size_t)b * V + v];
    if (x > m) { s = s * expf(m - x) + 1.f; m = x; }
    else s += expf(x - m);
  }
  rm[t] = m; rs[t] = s; __syncthreads();
  for (int off = 128; off; off >>= 1) {
    if (t < off) {
      float m1 = rm[t], s1 = rs[t], m2 = rm[t + off], s2 = rs[t + off];
      float M = fmaxf(m1, m2);
      rm[t] = M; rs[t] = s1 * expf(m1 - M) + s2 * expf(m2 - M);
    }
    __syncthreads();
  }
  if (t == 0) { rmax[b] = rm[0]; rsum[b] = rs[0]; }
}

__global__ void k_probs(const float* __restrict__ logits, const float* __restrict__ rmax,
    const float* __restrict__ rsum, const float* __restrict__ probptr,
    float* __restrict__ outp, int V, int ext)
{
  int b = blockIdx.y;
  int v = (int)blockIdx.x * 256 + threadIdx.x;
  if (v >= ext) return;
  float val = 0.f;
  if (v < V) {
    float pg = 1.f - probptr[b];
    val = pg * expf(logits[(size_t)b * V + v] - rmax[b]) / rsum[b];
  }
  outp[(size_t)b * ext + v] = val;
}

__global__ void k_scatter(const int* __restrict__ widx, const float* __restrict__ attn,
    const float* __restrict__ probptr, float* __restrict__ outp, int ext)
{
  int i = (int)blockIdx.x * 256 + threadIdx.x;
  if (i >= 128 * 400) return;
  int b = i / 400;
  atomicAdd(&outp[(size_t)b * ext + widx[i]], probptr[b] * attn[i]);
}

__global__ void k_log(float* __restrict__ outp, int n)
{
  int i = (int)blockIdx.x * 256 + threadIdx.x;
  if (i < n) outp[i] = logf(outp[i] + 1e-31f);
}

// ---------------- host ----------------
extern "C" void kernel_launch(void* const* d_in, const int* in_sizes, int n_in,
                              void* d_out, int out_size, void* d_ws, size_t ws_size,
                              hipStream_t stream) {
  const float* emb   = (const float*)d_in[0];
  const float* h0    = (const float*)d_in[1];
  const float* c0    = (const float*)d_in[2];
  const float* enc   = (const float*)d_in[3];
  const float* cov   = (const float*)d_in[4];
  const float* mask  = (const float*)d_in[5];
  const int*   widx  = (const int*)d_in[6];
  const float* pctx  = (const float*)d_in[7];
  const float* fcW   = (const float*)d_in[9];
  const float* fcB   = (const float*)d_in[10];
  const float* Wih   = (const float*)d_in[11];
  const float* Whh   = (const float*)d_in[12];
  const float* bih   = (const float*)d_in[13];
  const float* bhh   = (const float*)d_in[14];
  const float* attnW = (const float*)d_in[15];
  const float* W2    = (const float*)d_in[16];
  const float* W3    = (const float*)d_in[17];
  const float* cw    = (const float*)d_in[18];
  const float* ptrW  = (const float*)d_in[19];
  const float* ptrB  = (const float*)d_in[20];
  const float* outW  = (const float*)d_in[21];

  const int V   = in_sizes[21] / 1024;                        // 50000
  const int ext = (out_size - 128 * (1024 + 400 + 1)) / 128;  // 50100

  // ws layout (floats). logits aliases the small temporaries (all dead
  // before k_logits runs): dec_emb@0, gates@65536, hq@327680, ctx4@393216,
  // att4@655360 — ends 860160 < 6.4M. Total ws use: 26.4 MB.
  float* F       = (float*)d_ws;
  float* logits  = F;                 // 128*V = 6,400,000
  float* dec_emb = F;                 // 65536 (dead before k_logits)
  float* gates   = F + 65536;         // 262144
  float* hq      = F + 327680;        // 65536
  float* ctx4    = F + 393216;        // 4*65536 = 262144
  float* att4    = F + 655360;        // 4*51200 = 204800 -> 860160
  float* rmax    = F + 6400000;       // 128
  float* rsum    = F + 6400128;       // 128
  unsigned short* w2t  = (unsigned short*)(F + 6400256);  // 262144 bf16 (131072 f)
  unsigned short* comb = (unsigned short*)(F + 6531328);  // 131072 bf16 (65536 f)
  // total: 6,596,864 floats = 26.4 MB

  float* outp    = (float*)d_out;
  float* o_probs = outp;
  float* o_h     = outp + (size_t)128 * ext;
  float* o_c     = o_h + 65536;
  float* o_attn  = o_c + 65536;
  float* o_pp    = o_attn + 51200;

  k_w2t     <<<256, 256, 0, stream>>>(W2, w2t);
  k_fcdec   <<<256, 256, 0, stream>>>(emb, pctx, fcW, fcB, dec_emb);
  k_gates   <<<1024, 256, 0, stream>>>(dec_emb, h0, Wih, Whh, bih, bhh, gates);
  k_lstm    <<<256, 256, 0, stream>>>(gates, c0, o_h, o_c);
  k_hq      <<<64, 256, 0, stream>>>(o_h, o_c, attnW, hq);
  k_energy  <<<1600, 256, 0, stream>>>(enc, w2t, hq, cov, cw, W3, att4);
  k_asoftmax<<<128, 256, 0, stream>>>(att4, mask, o_attn);
  k_ctx     <<<512, 256, 0, stream>>>(enc, o_attn, ctx4);
  k_comb    <<<128, 256, 0, stream>>>(o_h, ctx4, emb, ptrW, ptrB, comb, o_pp);
  k_logits  <<<(V + 63) / 64, 256, 0, stream>>>(comb, outW, logits, V);
  k_rowstat <<<128, 256, 0, stream>>>(logits, rmax, rsum, V);
  dim3 gp((ext + 255) / 256, 128);
  k_probs   <<<gp, 256, 0, stream>>>(logits, rmax, rsum, o_pp, o_probs, V, ext);
  k_scatter <<<200, 256, 0, stream>>>(widx, o_attn, o_pp, o_probs, ext);
  k_log     <<<(128 * ext + 255) / 256, 256, 0, stream>>>(o_probs, 128 * ext);
}